// Round 11
// baseline (103.725 us; speedup 1.0000x reference)
//
#include <hip/hip_runtime.h>

#define ROWS   681408        // 64 * 10647
#define NBINS  8192
#define CAP    64            // bucket capacity per bin
#define TOPK   192
#define SELCAP 256
#define RPB    128           // rows per block (2 rows per quad)
#define NBLK   ((ROWS + RPB - 1) / RPB)   // 5324

// ws word offsets
#define WS_ROW0     4        // 6 floats: score, class, x1,y1,x2,y2
#define WS_CNT      16       // 8192 uints -> words 16..8207 (16B aligned)
#define WS_BUCKET   8448     // uint2[NBINS*CAP] -> 1,048,576 words (4 MB)

typedef float floatx4 __attribute__((ext_vector_type(4)));

__device__ __forceinline__ float clip01(float v) {
    return fminf(fmaxf(v, 0.0f), 1.0f);
}

__device__ __forceinline__ float4 ntload4(const float4* p) {
    floatx4 v = __builtin_nontemporal_load((const floatx4*)p);
    return make_float4(v.x, v.y, v.z, v.w);
}

__global__ __launch_bounds__(256) void decode_kernel(
    const float* __restrict__ y, unsigned int* __restrict__ ws)
{
    const int t    = threadIdx.x;
    const int lane = t & 63;
    const int wv   = t >> 6;
    const int s    = lane & 3;        // quad slot 0..3
    const int qr   = lane >> 2;       // quad within wave 0..15
    const unsigned int r0 = blockIdx.x * RPB + wv * 32 + qr * 2;
    if (r0 >= (unsigned int)ROWS) return;   // quad-uniform (ROWS even, pairs intact)
    const unsigned int r1 = r0 + 1;

    const float*  pA = y + (size_t)r0 * 85;
    const float*  pB = pA + 85;
    const float4* a4 = (const float4*)pA;   // dword-aligned float4: OK on gfx9+
    const float4* b4 = (const float4*)pB;

    // issue all loads for both rows up-front (independent, deep MLP)
    float4 A0 = ntload4(a4 + s);
    float4 A1 = ntload4(a4 + s + 4);
    float4 A2 = ntload4(a4 + s + 8);
    float4 A3 = ntload4(a4 + s + 12);
    float4 A4 = ntload4(a4 + s + 16);
    float4 B0 = ntload4(b4 + s);
    float4 B1 = ntload4(b4 + s + 4);
    float4 B2 = ntload4(b4 + s + 8);
    float4 B3 = ntload4(b4 + s + 12);
    float4 B4 = ntload4(b4 + s + 16);
    float4 At = make_float4(-1.0f, -1.0f, -1.0f, -1.0f);
    float4 Bt = At;
    float a84 = -1.0f, b84 = -1.0f;
    if (s == 0) { At = ntload4(a4 + 20); Bt = ntload4(b4 + 20); }
    if (s == 1) { a84 = pA[84]; b84 = pB[84]; }

    // per-lane argmax over probs (elems 5..84), ascending element order,
    // strict > (first-index-wins == jnp.argmax); classes partition lanes.
    const int b0 = 4 * s;
    float bvA = -1.0f; int bcA = 1 << 20;
    {
        if (b0 + 0 >= 5 && A0.x > bvA) { bvA = A0.x; bcA = b0 - 5; }
        if (b0 + 1 >= 5 && A0.y > bvA) { bvA = A0.y; bcA = b0 - 4; }
        if (b0 + 2 >= 5 && A0.z > bvA) { bvA = A0.z; bcA = b0 - 3; }
        if (b0 + 3 >= 5 && A0.w > bvA) { bvA = A0.w; bcA = b0 - 2; }
        if (A1.x > bvA) { bvA = A1.x; bcA = b0 + 11; }
        if (A1.y > bvA) { bvA = A1.y; bcA = b0 + 12; }
        if (A1.z > bvA) { bvA = A1.z; bcA = b0 + 13; }
        if (A1.w > bvA) { bvA = A1.w; bcA = b0 + 14; }
        if (A2.x > bvA) { bvA = A2.x; bcA = b0 + 27; }
        if (A2.y > bvA) { bvA = A2.y; bcA = b0 + 28; }
        if (A2.z > bvA) { bvA = A2.z; bcA = b0 + 29; }
        if (A2.w > bvA) { bvA = A2.w; bcA = b0 + 30; }
        if (A3.x > bvA) { bvA = A3.x; bcA = b0 + 43; }
        if (A3.y > bvA) { bvA = A3.y; bcA = b0 + 44; }
        if (A3.z > bvA) { bvA = A3.z; bcA = b0 + 45; }
        if (A3.w > bvA) { bvA = A3.w; bcA = b0 + 46; }
        if (A4.x > bvA) { bvA = A4.x; bcA = b0 + 59; }
        if (A4.y > bvA) { bvA = A4.y; bcA = b0 + 60; }
        if (A4.z > bvA) { bvA = A4.z; bcA = b0 + 61; }
        if (A4.w > bvA) { bvA = A4.w; bcA = b0 + 62; }
        if (s == 0) {
            if (At.x > bvA) { bvA = At.x; bcA = 75; }
            if (At.y > bvA) { bvA = At.y; bcA = 76; }
            if (At.z > bvA) { bvA = At.z; bcA = 77; }
            if (At.w > bvA) { bvA = At.w; bcA = 78; }
        }
        if (s == 1 && a84 > bvA) { bvA = a84; bcA = 79; }
    }
    float bvB = -1.0f; int bcB = 1 << 20;
    {
        if (b0 + 0 >= 5 && B0.x > bvB) { bvB = B0.x; bcB = b0 - 5; }
        if (b0 + 1 >= 5 && B0.y > bvB) { bvB = B0.y; bcB = b0 - 4; }
        if (b0 + 2 >= 5 && B0.z > bvB) { bvB = B0.z; bcB = b0 - 3; }
        if (b0 + 3 >= 5 && B0.w > bvB) { bvB = B0.w; bcB = b0 - 2; }
        if (B1.x > bvB) { bvB = B1.x; bcB = b0 + 11; }
        if (B1.y > bvB) { bvB = B1.y; bcB = b0 + 12; }
        if (B1.z > bvB) { bvB = B1.z; bcB = b0 + 13; }
        if (B1.w > bvB) { bvB = B1.w; bcB = b0 + 14; }
        if (B2.x > bvB) { bvB = B2.x; bcB = b0 + 27; }
        if (B2.y > bvB) { bvB = B2.y; bcB = b0 + 28; }
        if (B2.z > bvB) { bvB = B2.z; bcB = b0 + 29; }
        if (B2.w > bvB) { bvB = B2.w; bcB = b0 + 30; }
        if (B3.x > bvB) { bvB = B3.x; bcB = b0 + 43; }
        if (B3.y > bvB) { bvB = B3.y; bcB = b0 + 44; }
        if (B3.z > bvB) { bvB = B3.z; bcB = b0 + 45; }
        if (B3.w > bvB) { bvB = B3.w; bcB = b0 + 46; }
        if (B4.x > bvB) { bvB = B4.x; bcB = b0 + 59; }
        if (B4.y > bvB) { bvB = B4.y; bcB = b0 + 60; }
        if (B4.z > bvB) { bvB = B4.z; bcB = b0 + 61; }
        if (B4.w > bvB) { bvB = B4.w; bcB = b0 + 62; }
        if (s == 0) {
            if (Bt.x > bvB) { bvB = Bt.x; bcB = 75; }
            if (Bt.y > bvB) { bvB = Bt.y; bcB = 76; }
            if (Bt.z > bvB) { bvB = Bt.z; bcB = 77; }
            if (Bt.w > bvB) { bvB = Bt.w; bcB = 78; }
        }
        if (s == 1 && b84 > bvB) { bvB = b84; bcB = 79; }
    }

    // quad reductions with min-class tie-break (exact argmax semantics)
    #pragma unroll
    for (int m = 1; m <= 2; m <<= 1) {
        float ov = __shfl_xor(bvA, m, 64);
        int   oc = __shfl_xor(bcA, m, 64);
        if (ov > bvA || (ov == bvA && oc < bcA)) { bvA = ov; bcA = oc; }
        float ow = __shfl_xor(bvB, m, 64);
        int   od = __shfl_xor(bcB, m, 64);
        if (ow > bvB || (ow == bvB && od < bcB)) { bvB = ow; bcB = od; }
    }

    const int ql = (lane & 60) + 1;        // quad's lane 1
    float cfA = __shfl(A0.x, ql, 64);      // elem 4 of row A
    float cfB = __shfl(B0.x, ql, 64);      // elem 4 of row B

    if (s == 0) {
        uint2* bucket = (uint2*)&ws[WS_BUCKET];
        // ---- row A (box = this lane's A0)
        {
            float score = cfA * bvA;
            float x  = clip01(A0.x / 416.0f);
            float yy = clip01(A0.y / 416.0f);
            float w  = clip01(A0.z / 416.0f);
            float h  = clip01(A0.w / 416.0f);
            float x1 = clip01(x  - w * 0.5f);
            float y1 = clip01(yy - h * 0.5f);
            float x2 = clip01(x  + w * 0.5f);
            float y2 = clip01(yy + h * 0.5f);
            bool keep = (((x2 - x1) * (y2 - y1)) > 0.0005f) && (score > 0.5f);
            if (keep) {
                int bin = (int)((score - 0.5f) * (2.0f * (float)NBINS));
                bin = min(max(bin, 0), NBINS - 1);
                unsigned int pos = atomicAdd(&ws[WS_CNT + bin], 1u);
                if (pos < (unsigned int)CAP)
                    bucket[bin * CAP + pos] =
                        make_uint2(__float_as_uint(score), r0);
            }
            if (r0 == 0) {
                float* w0 = (float*)&ws[WS_ROW0];
                w0[0] = score; w0[1] = (float)bcA;
                w0[2] = x1; w0[3] = y1; w0[4] = x2; w0[5] = y2;
            }
        }
        // ---- row B (box = this lane's B0)
        {
            float score = cfB * bvB;
            float x  = clip01(B0.x / 416.0f);
            float yy = clip01(B0.y / 416.0f);
            float w  = clip01(B0.z / 416.0f);
            float h  = clip01(B0.w / 416.0f);
            float x1 = clip01(x  - w * 0.5f);
            float y1 = clip01(yy - h * 0.5f);
            float x2 = clip01(x  + w * 0.5f);
            float y2 = clip01(yy + h * 0.5f);
            bool keep = (((x2 - x1) * (y2 - y1)) > 0.0005f) && (score > 0.5f);
            if (keep) {
                int bin = (int)((score - 0.5f) * (2.0f * (float)NBINS));
                bin = min(max(bin, 0), NBINS - 1);
                unsigned int pos = atomicAdd(&ws[WS_CNT + bin], 1u);
                if (pos < (unsigned int)CAP)
                    bucket[bin * CAP + pos] =
                        make_uint2(__float_as_uint(score), r1);
            }
        }
    }
}

__global__ __launch_bounds__(256) void nms_kernel(
    const float* __restrict__ y, unsigned int* __restrict__ ws,
    float* __restrict__ out)
{
    __shared__ unsigned int chunk[256];
    __shared__ unsigned int fine[32];
    __shared__ unsigned long long keys[SELCAP];
    __shared__ float4 sboxes[SELCAP];
    __shared__ int s_coarse;
    __shared__ int s_bstar;
    __shared__ unsigned int s_m;
    __shared__ int s_picks;
    __shared__ unsigned int s_idx[10];
    __shared__ float s_score[10];
    __shared__ float4 s_box[10];
    __shared__ int s_cls[10];

    const int t = threadIdx.x;
    const uint2* bucket = (const uint2*)&ws[WS_BUCKET];

    // ---- per-chunk clamped counts (32 bins per thread, vectorized)
    unsigned int ssum = 0;
    {
        const uint4* cnt4 = (const uint4*)&ws[WS_CNT];
        #pragma unroll
        for (int i = 0; i < 8; i++) {
            uint4 v = cnt4[t * 8 + i];
            ssum += min(v.x, (unsigned int)CAP) + min(v.y, (unsigned int)CAP)
                  + min(v.z, (unsigned int)CAP) + min(v.w, (unsigned int)CAP);
        }
    }
    chunk[t] = ssum;
    for (int i = t; i < SELCAP; i += 256) keys[i] = 0ull;
    if (t == 0) s_m = 0u;
    __syncthreads();

    // ---- parallel suffix sum over the 256 chunks (Hillis-Steele)
    for (int off = 1; off < 256; off <<= 1) {
        unsigned int v = chunk[t];
        unsigned int a = (t + off < 256) ? chunk[t + off] : 0u;
        __syncthreads();
        chunk[t] = v + a;
        __syncthreads();
    }
    const unsigned int total  = chunk[0];
    const unsigned int target = (total < (unsigned int)TOPK) ? total
                                                             : (unsigned int)TOPK;

    if (target > 0) {           // block-uniform branch; barriers inside are legal
        if (chunk[t] >= target && (t == 255 || chunk[t + 1] < target))
            s_coarse = t;
        __syncthreads();

        const int cb = s_coarse * 32;
        if (t < 32) fine[t] = min(ws[WS_CNT + cb + t], (unsigned int)CAP);
        __syncthreads();
        for (int off = 1; off < 32; off <<= 1) {
            unsigned int v = 0, a = 0;
            if (t < 32) { v = fine[t]; a = (t + off < 32) ? fine[t + off] : 0u; }
            __syncthreads();
            if (t < 32) fine[t] = v + a;
            __syncthreads();
        }
        const unsigned int base = (s_coarse < 255) ? chunk[s_coarse + 1] : 0u;
        if (t < 32) {
            unsigned int sfx = base + fine[t];
            unsigned int nxt = (t == 31) ? base : base + fine[t + 1];
            if (sfx >= target && nxt < target) s_bstar = cb + t;
        }
    } else {
        if (t == 0) s_bstar = NBINS;
    }
    __syncthreads();

    // ---- gather all entries from bins >= b*
    for (int bin = s_bstar + t; bin < NBINS; bin += 256) {
        unsigned int c = ws[WS_CNT + bin];
        if (c > (unsigned int)CAP) c = CAP;
        for (unsigned int j = 0; j < c; j++) {
            uint2 cv = bucket[bin * CAP + j];
            unsigned int pos = atomicAdd(&s_m, 1u);
            if (pos < (unsigned int)SELCAP)
                keys[pos] = ((unsigned long long)cv.x << 32) |
                            (unsigned long long)(0xFFFFFFFFu - cv.y);
        }
    }
    __syncthreads();
    unsigned int M = s_m;
    if (M > (unsigned int)SELCAP) M = SELCAP;

    // ---- bitonic sort, descending: (score desc, idx asc)
    for (int k = 2; k <= SELCAP; k <<= 1) {
        for (int j = k >> 1; j > 0; j >>= 1) {
            for (int i = t; i < SELCAP; i += 256) {
                int ixj = i ^ j;
                if (ixj > i) {
                    unsigned long long a = keys[i], b = keys[ixj];
                    bool descSeg = ((i & k) == 0);
                    if (descSeg ? (a < b) : (a > b)) { keys[i] = b; keys[ixj] = a; }
                }
            }
            __syncthreads();
        }
    }

    // ---- decode boxes for the sorted prefix
    for (int i = t; i < (int)M; i += 256) {
        unsigned int idx = 0xFFFFFFFFu - (unsigned int)(keys[i] & 0xFFFFFFFFull);
        const float* p = y + (size_t)idx * 85;
        float x  = clip01(p[0] / 416.0f);
        float yy = clip01(p[1] / 416.0f);
        float w  = clip01(p[2] / 416.0f);
        float h  = clip01(p[3] / 416.0f);
        sboxes[i] = make_float4(clip01(x - w * 0.5f), clip01(yy - h * 0.5f),
                                clip01(x + w * 0.5f), clip01(yy + h * 0.5f));
    }
    __syncthreads();

    // ---- sequential greedy-NMS scan (exact equivalent of the 10-step argmax loop)
    if (t == 0) {
        int np = 0;
        for (int i = 0; i < (int)M && np < 10; i++) {
            float4 b = sboxes[i];
            bool ok = true;
            for (int kk = 0; kk < np; kk++) {
                float4 r = s_box[kk];
                float ix1 = fmaxf(r.x, b.x);
                float iy1 = fmaxf(r.y, b.y);
                float ix2 = fminf(r.z, b.z);
                float iy2 = fminf(r.w, b.w);
                float inter = fmaxf(ix2 - ix1, 0.0f) * fmaxf(iy2 - iy1, 0.0f);
                float aref = (r.z - r.x) * (r.w - r.y);
                float aall = (b.z - b.x) * (b.w - b.y);
                float iou = inter / (aref + aall - inter + 1e-10f);
                if (iou > 0.45f) { ok = false; break; }
            }
            if (ok) {
                s_box[np] = b;
                s_idx[np] = 0xFFFFFFFFu - (unsigned int)(keys[i] & 0xFFFFFFFFull);
                s_score[np] = __uint_as_float((unsigned int)(keys[i] >> 32));
                np++;
            }
        }
        s_picks = np;
    }
    __syncthreads();

    // ---- class (argmax of 80 probs) for each pick: 16 lanes per pick
    {
        int p = t >> 4, s = t & 15;
        float bv = -1.0f; int bc = 1 << 20;
        if (p < s_picks) {
            const float* pr = y + (size_t)s_idx[p] * 85 + 5;
            #pragma unroll
            for (int kk = 0; kk < 5; kk++) {
                float v = pr[s + 16 * kk];
                int c = s + 16 * kk;
                if (v > bv) { bv = v; bc = c; }
            }
        }
        #pragma unroll
        for (int m = 8; m >= 1; m >>= 1) {
            float ov = __shfl_xor(bv, m, 64);
            int   oc = __shfl_xor(bc, m, 64);
            if (ov > bv || (ov == bv && oc < bc)) { bv = ov; bc = oc; }
        }
        if (p < s_picks && s == 0) s_cls[p] = bc;
    }
    __syncthreads();

    if (t == 0) {
        const float* r0 = (const float*)&ws[WS_ROW0];
        float score0 = r0[0], class0 = r0[1];
        float4 box0 = make_float4(r0[2], r0[3], r0[4], r0[5]);
        for (int kk = 0; kk < 10; kk++) {
            bool v = kk < s_picks;
            float4 b = v ? s_box[kk] : box0;
            out[4 * kk + 0] = b.x;
            out[4 * kk + 1] = b.y;
            out[4 * kk + 2] = b.z;
            out[4 * kk + 3] = b.w;
            out[40 + kk] = v ? s_score[kk] : score0;
            out[50 + kk] = v ? (float)s_cls[kk] : class0;
            out[60 + kk] = v ? 1.0f : 0.0f;
        }
    }
}

extern "C" void kernel_launch(void* const* d_in, const int* in_sizes, int n_in,
                              void* d_out, int out_size, void* d_ws, size_t ws_size,
                              hipStream_t stream)
{
    const float* y = (const float*)d_in[0];
    unsigned int* ws = (unsigned int*)d_ws;

    // zero counters + ROW0 area (words 0..8207) — replaces the init kernel
    (void)hipMemsetAsync(d_ws, 0, (WS_CNT + NBINS) * sizeof(unsigned int), stream);
    decode_kernel<<<dim3(NBLK), dim3(256), 0, stream>>>(y, ws);
    nms_kernel<<<dim3(1), dim3(256), 0, stream>>>(y, ws, (float*)d_out);
}

// Round 12
// 70.399 us; speedup vs baseline: 1.4734x; 1.4734x over previous
//
#include <hip/hip_runtime.h>

#define ROWS   681408        // 64 * 10647
#define NBINS  8192
#define CAP    64            // bucket capacity per bin
#define TOPK   192
#define SELCAP 256
#define RPB    128           // rows per block (2 rows per quad)
#define NBLK   ((ROWS + RPB - 1) / RPB)   // 5324

// ws word offsets
#define WS_ROW0     4        // 6 floats: score, class, x1,y1,x2,y2
#define WS_CNT      16       // 8192 uints -> words 16..8207 (16B aligned)
#define WS_BUCKET   8448     // uint2[NBINS*CAP] -> 1,048,576 words (4 MB)

__device__ __forceinline__ float clip01(float v) {
    return fminf(fmaxf(v, 0.0f), 1.0f);
}

__global__ __launch_bounds__(256) void decode_kernel(
    const float* __restrict__ y, unsigned int* __restrict__ ws)
{
    const int t    = threadIdx.x;
    const int lane = t & 63;
    const int wv   = t >> 6;
    const int s    = lane & 3;        // quad slot 0..3
    const int qr   = lane >> 2;       // quad within wave 0..15
    const unsigned int r0 = blockIdx.x * RPB + wv * 32 + qr * 2;
    if (r0 >= (unsigned int)ROWS) return;   // quad-uniform (ROWS even, pairs intact)
    const unsigned int r1 = r0 + 1;

    const float*  pA = y + (size_t)r0 * 85;
    const float*  pB = pA + 85;
    const float4* a4 = (const float4*)pA;   // dword-aligned float4: OK on gfx9+
    const float4* b4 = (const float4*)pB;

    // issue all loads for both rows up-front (independent, deep MLP), cached
    float4 A0 = a4[s];
    float4 A1 = a4[s + 4];
    float4 A2 = a4[s + 8];
    float4 A3 = a4[s + 12];
    float4 A4 = a4[s + 16];
    float4 B0 = b4[s];
    float4 B1 = b4[s + 4];
    float4 B2 = b4[s + 8];
    float4 B3 = b4[s + 12];
    float4 B4 = b4[s + 16];
    float4 At = make_float4(-1.0f, -1.0f, -1.0f, -1.0f);
    float4 Bt = At;
    float a84 = -1.0f, b84 = -1.0f;
    if (s == 0) { At = a4[20]; Bt = b4[20]; }
    if (s == 1) { a84 = pA[84]; b84 = pB[84]; }

    // per-lane argmax over probs (elems 5..84), ascending element order,
    // strict > (first-index-wins == jnp.argmax); classes partition lanes.
    const int b0 = 4 * s;
    float bvA = -1.0f; int bcA = 1 << 20;
    {
        if (b0 + 0 >= 5 && A0.x > bvA) { bvA = A0.x; bcA = b0 - 5; }
        if (b0 + 1 >= 5 && A0.y > bvA) { bvA = A0.y; bcA = b0 - 4; }
        if (b0 + 2 >= 5 && A0.z > bvA) { bvA = A0.z; bcA = b0 - 3; }
        if (b0 + 3 >= 5 && A0.w > bvA) { bvA = A0.w; bcA = b0 - 2; }
        if (A1.x > bvA) { bvA = A1.x; bcA = b0 + 11; }
        if (A1.y > bvA) { bvA = A1.y; bcA = b0 + 12; }
        if (A1.z > bvA) { bvA = A1.z; bcA = b0 + 13; }
        if (A1.w > bvA) { bvA = A1.w; bcA = b0 + 14; }
        if (A2.x > bvA) { bvA = A2.x; bcA = b0 + 27; }
        if (A2.y > bvA) { bvA = A2.y; bcA = b0 + 28; }
        if (A2.z > bvA) { bvA = A2.z; bcA = b0 + 29; }
        if (A2.w > bvA) { bvA = A2.w; bcA = b0 + 30; }
        if (A3.x > bvA) { bvA = A3.x; bcA = b0 + 43; }
        if (A3.y > bvA) { bvA = A3.y; bcA = b0 + 44; }
        if (A3.z > bvA) { bvA = A3.z; bcA = b0 + 45; }
        if (A3.w > bvA) { bvA = A3.w; bcA = b0 + 46; }
        if (A4.x > bvA) { bvA = A4.x; bcA = b0 + 59; }
        if (A4.y > bvA) { bvA = A4.y; bcA = b0 + 60; }
        if (A4.z > bvA) { bvA = A4.z; bcA = b0 + 61; }
        if (A4.w > bvA) { bvA = A4.w; bcA = b0 + 62; }
        if (s == 0) {
            if (At.x > bvA) { bvA = At.x; bcA = 75; }
            if (At.y > bvA) { bvA = At.y; bcA = 76; }
            if (At.z > bvA) { bvA = At.z; bcA = 77; }
            if (At.w > bvA) { bvA = At.w; bcA = 78; }
        }
        if (s == 1 && a84 > bvA) { bvA = a84; bcA = 79; }
    }
    float bvB = -1.0f; int bcB = 1 << 20;
    {
        if (b0 + 0 >= 5 && B0.x > bvB) { bvB = B0.x; bcB = b0 - 5; }
        if (b0 + 1 >= 5 && B0.y > bvB) { bvB = B0.y; bcB = b0 - 4; }
        if (b0 + 2 >= 5 && B0.z > bvB) { bvB = B0.z; bcB = b0 - 3; }
        if (b0 + 3 >= 5 && B0.w > bvB) { bvB = B0.w; bcB = b0 - 2; }
        if (B1.x > bvB) { bvB = B1.x; bcB = b0 + 11; }
        if (B1.y > bvB) { bvB = B1.y; bcB = b0 + 12; }
        if (B1.z > bvB) { bvB = B1.z; bcB = b0 + 13; }
        if (B1.w > bvB) { bvB = B1.w; bcB = b0 + 14; }
        if (B2.x > bvB) { bvB = B2.x; bcB = b0 + 27; }
        if (B2.y > bvB) { bvB = B2.y; bcB = b0 + 28; }
        if (B2.z > bvB) { bvB = B2.z; bcB = b0 + 29; }
        if (B2.w > bvB) { bvB = B2.w; bcB = b0 + 30; }
        if (B3.x > bvB) { bvB = B3.x; bcB = b0 + 43; }
        if (B3.y > bvB) { bvB = B3.y; bcB = b0 + 44; }
        if (B3.z > bvB) { bvB = B3.z; bcB = b0 + 45; }
        if (B3.w > bvB) { bvB = B3.w; bcB = b0 + 46; }
        if (B4.x > bvB) { bvB = B4.x; bcB = b0 + 59; }
        if (B4.y > bvB) { bvB = B4.y; bcB = b0 + 60; }
        if (B4.z > bvB) { bvB = B4.z; bcB = b0 + 61; }
        if (B4.w > bvB) { bvB = B4.w; bcB = b0 + 62; }
        if (s == 0) {
            if (Bt.x > bvB) { bvB = Bt.x; bcB = 75; }
            if (Bt.y > bvB) { bvB = Bt.y; bcB = 76; }
            if (Bt.z > bvB) { bvB = Bt.z; bcB = 77; }
            if (Bt.w > bvB) { bvB = Bt.w; bcB = 78; }
        }
        if (s == 1 && b84 > bvB) { bvB = b84; bcB = 79; }
    }

    // quad reductions with min-class tie-break (exact argmax semantics)
    #pragma unroll
    for (int m = 1; m <= 2; m <<= 1) {
        float ov = __shfl_xor(bvA, m, 64);
        int   oc = __shfl_xor(bcA, m, 64);
        if (ov > bvA || (ov == bvA && oc < bcA)) { bvA = ov; bcA = oc; }
        float ow = __shfl_xor(bvB, m, 64);
        int   od = __shfl_xor(bcB, m, 64);
        if (ow > bvB || (ow == bvB && od < bcB)) { bvB = ow; bcB = od; }
    }

    const int ql = (lane & 60) + 1;        // quad's lane 1
    float cfA = __shfl(A0.x, ql, 64);      // elem 4 of row A
    float cfB = __shfl(B0.x, ql, 64);      // elem 4 of row B

    if (s == 0) {
        uint2* bucket = (uint2*)&ws[WS_BUCKET];
        // ---- row A (box = this lane's A0)
        {
            float score = cfA * bvA;
            float x  = clip01(A0.x / 416.0f);
            float yy = clip01(A0.y / 416.0f);
            float w  = clip01(A0.z / 416.0f);
            float h  = clip01(A0.w / 416.0f);
            float x1 = clip01(x  - w * 0.5f);
            float y1 = clip01(yy - h * 0.5f);
            float x2 = clip01(x  + w * 0.5f);
            float y2 = clip01(yy + h * 0.5f);
            bool keep = (((x2 - x1) * (y2 - y1)) > 0.0005f) && (score > 0.5f);
            if (keep) {
                int bin = (int)((score - 0.5f) * (2.0f * (float)NBINS));
                bin = min(max(bin, 0), NBINS - 1);
                unsigned int pos = atomicAdd(&ws[WS_CNT + bin], 1u);
                if (pos < (unsigned int)CAP)
                    bucket[bin * CAP + pos] =
                        make_uint2(__float_as_uint(score), r0);
            }
            if (r0 == 0) {
                float* w0 = (float*)&ws[WS_ROW0];
                w0[0] = score; w0[1] = (float)bcA;
                w0[2] = x1; w0[3] = y1; w0[4] = x2; w0[5] = y2;
            }
        }
        // ---- row B (box = this lane's B0)
        {
            float score = cfB * bvB;
            float x  = clip01(B0.x / 416.0f);
            float yy = clip01(B0.y / 416.0f);
            float w  = clip01(B0.z / 416.0f);
            float h  = clip01(B0.w / 416.0f);
            float x1 = clip01(x  - w * 0.5f);
            float y1 = clip01(yy - h * 0.5f);
            float x2 = clip01(x  + w * 0.5f);
            float y2 = clip01(yy + h * 0.5f);
            bool keep = (((x2 - x1) * (y2 - y1)) > 0.0005f) && (score > 0.5f);
            if (keep) {
                int bin = (int)((score - 0.5f) * (2.0f * (float)NBINS));
                bin = min(max(bin, 0), NBINS - 1);
                unsigned int pos = atomicAdd(&ws[WS_CNT + bin], 1u);
                if (pos < (unsigned int)CAP)
                    bucket[bin * CAP + pos] =
                        make_uint2(__float_as_uint(score), r1);
            }
        }
    }
}

__global__ __launch_bounds__(256) void nms_kernel(
    const float* __restrict__ y, unsigned int* __restrict__ ws,
    float* __restrict__ out)
{
    __shared__ unsigned int chunk[256];
    __shared__ unsigned int fine[32];
    __shared__ unsigned long long keys[SELCAP];
    __shared__ float4 sboxes[SELCAP];
    __shared__ int s_coarse;
    __shared__ int s_bstar;
    __shared__ unsigned int s_m;
    __shared__ int s_picks;
    __shared__ unsigned int s_idx[10];
    __shared__ float s_score[10];
    __shared__ float4 s_box[10];
    __shared__ int s_cls[10];

    const int t = threadIdx.x;
    const uint2* bucket = (const uint2*)&ws[WS_BUCKET];

    // ---- per-chunk clamped counts (32 bins per thread, vectorized)
    unsigned int ssum = 0;
    {
        const uint4* cnt4 = (const uint4*)&ws[WS_CNT];
        #pragma unroll
        for (int i = 0; i < 8; i++) {
            uint4 v = cnt4[t * 8 + i];
            ssum += min(v.x, (unsigned int)CAP) + min(v.y, (unsigned int)CAP)
                  + min(v.z, (unsigned int)CAP) + min(v.w, (unsigned int)CAP);
        }
    }
    chunk[t] = ssum;
    for (int i = t; i < SELCAP; i += 256) keys[i] = 0ull;
    if (t == 0) s_m = 0u;
    __syncthreads();

    // ---- parallel suffix sum over the 256 chunks (Hillis-Steele)
    for (int off = 1; off < 256; off <<= 1) {
        unsigned int v = chunk[t];
        unsigned int a = (t + off < 256) ? chunk[t + off] : 0u;
        __syncthreads();
        chunk[t] = v + a;
        __syncthreads();
    }
    const unsigned int total  = chunk[0];
    const unsigned int target = (total < (unsigned int)TOPK) ? total
                                                             : (unsigned int)TOPK;

    if (target > 0) {           // block-uniform branch; barriers inside are legal
        if (chunk[t] >= target && (t == 255 || chunk[t + 1] < target))
            s_coarse = t;
        __syncthreads();

        const int cb = s_coarse * 32;
        if (t < 32) fine[t] = min(ws[WS_CNT + cb + t], (unsigned int)CAP);
        __syncthreads();
        for (int off = 1; off < 32; off <<= 1) {
            unsigned int v = 0, a = 0;
            if (t < 32) { v = fine[t]; a = (t + off < 32) ? fine[t + off] : 0u; }
            __syncthreads();
            if (t < 32) fine[t] = v + a;
            __syncthreads();
        }
        const unsigned int base = (s_coarse < 255) ? chunk[s_coarse + 1] : 0u;
        if (t < 32) {
            unsigned int sfx = base + fine[t];
            unsigned int nxt = (t == 31) ? base : base + fine[t + 1];
            if (sfx >= target && nxt < target) s_bstar = cb + t;
        }
    } else {
        if (t == 0) s_bstar = NBINS;
    }
    __syncthreads();

    // ---- gather all entries from bins >= b*
    for (int bin = s_bstar + t; bin < NBINS; bin += 256) {
        unsigned int c = ws[WS_CNT + bin];
        if (c > (unsigned int)CAP) c = CAP;
        for (unsigned int j = 0; j < c; j++) {
            uint2 cv = bucket[bin * CAP + j];
            unsigned int pos = atomicAdd(&s_m, 1u);
            if (pos < (unsigned int)SELCAP)
                keys[pos] = ((unsigned long long)cv.x << 32) |
                            (unsigned long long)(0xFFFFFFFFu - cv.y);
        }
    }
    __syncthreads();
    unsigned int M = s_m;
    if (M > (unsigned int)SELCAP) M = SELCAP;

    // ---- bitonic sort, descending: (score desc, idx asc)
    for (int k = 2; k <= SELCAP; k <<= 1) {
        for (int j = k >> 1; j > 0; j >>= 1) {
            for (int i = t; i < SELCAP; i += 256) {
                int ixj = i ^ j;
                if (ixj > i) {
                    unsigned long long a = keys[i], b = keys[ixj];
                    bool descSeg = ((i & k) == 0);
                    if (descSeg ? (a < b) : (a > b)) { keys[i] = b; keys[ixj] = a; }
                }
            }
            __syncthreads();
        }
    }

    // ---- decode boxes for the sorted prefix
    for (int i = t; i < (int)M; i += 256) {
        unsigned int idx = 0xFFFFFFFFu - (unsigned int)(keys[i] & 0xFFFFFFFFull);
        const float* p = y + (size_t)idx * 85;
        float x  = clip01(p[0] / 416.0f);
        float yy = clip01(p[1] / 416.0f);
        float w  = clip01(p[2] / 416.0f);
        float h  = clip01(p[3] / 416.0f);
        sboxes[i] = make_float4(clip01(x - w * 0.5f), clip01(yy - h * 0.5f),
                                clip01(x + w * 0.5f), clip01(yy + h * 0.5f));
    }
    __syncthreads();

    // ---- sequential greedy-NMS scan (exact equivalent of the 10-step argmax loop)
    if (t == 0) {
        int np = 0;
        for (int i = 0; i < (int)M && np < 10; i++) {
            float4 b = sboxes[i];
            bool ok = true;
            for (int kk = 0; kk < np; kk++) {
                float4 r = s_box[kk];
                float ix1 = fmaxf(r.x, b.x);
                float iy1 = fmaxf(r.y, b.y);
                float ix2 = fminf(r.z, b.z);
                float iy2 = fminf(r.w, b.w);
                float inter = fmaxf(ix2 - ix1, 0.0f) * fmaxf(iy2 - iy1, 0.0f);
                float aref = (r.z - r.x) * (r.w - r.y);
                float aall = (b.z - b.x) * (b.w - b.y);
                float iou = inter / (aref + aall - inter + 1e-10f);
                if (iou > 0.45f) { ok = false; break; }
            }
            if (ok) {
                s_box[np] = b;
                s_idx[np] = 0xFFFFFFFFu - (unsigned int)(keys[i] & 0xFFFFFFFFull);
                s_score[np] = __uint_as_float((unsigned int)(keys[i] >> 32));
                np++;
            }
        }
        s_picks = np;
    }
    __syncthreads();

    // ---- class (argmax of 80 probs) for each pick: 16 lanes per pick
    {
        int p = t >> 4, s = t & 15;
        float bv = -1.0f; int bc = 1 << 20;
        if (p < s_picks) {
            const float* pr = y + (size_t)s_idx[p] * 85 + 5;
            #pragma unroll
            for (int kk = 0; kk < 5; kk++) {
                float v = pr[s + 16 * kk];
                int c = s + 16 * kk;
                if (v > bv) { bv = v; bc = c; }
            }
        }
        #pragma unroll
        for (int m = 8; m >= 1; m >>= 1) {
            float ov = __shfl_xor(bv, m, 64);
            int   oc = __shfl_xor(bc, m, 64);
            if (ov > bv || (ov == bv && oc < bc)) { bv = ov; bc = oc; }
        }
        if (p < s_picks && s == 0) s_cls[p] = bc;
    }
    __syncthreads();

    if (t == 0) {
        const float* r0 = (const float*)&ws[WS_ROW0];
        float score0 = r0[0], class0 = r0[1];
        float4 box0 = make_float4(r0[2], r0[3], r0[4], r0[5]);
        for (int kk = 0; kk < 10; kk++) {
            bool v = kk < s_picks;
            float4 b = v ? s_box[kk] : box0;
            out[4 * kk + 0] = b.x;
            out[4 * kk + 1] = b.y;
            out[4 * kk + 2] = b.z;
            out[4 * kk + 3] = b.w;
            out[40 + kk] = v ? s_score[kk] : score0;
            out[50 + kk] = v ? (float)s_cls[kk] : class0;
            out[60 + kk] = v ? 1.0f : 0.0f;
        }
    }
}

extern "C" void kernel_launch(void* const* d_in, const int* in_sizes, int n_in,
                              void* d_out, int out_size, void* d_ws, size_t ws_size,
                              hipStream_t stream)
{
    const float* y = (const float*)d_in[0];
    unsigned int* ws = (unsigned int*)d_ws;

    // zero counters + ROW0 area (words 0..8207) — replaces the init kernel
    (void)hipMemsetAsync(d_ws, 0, (WS_CNT + NBINS) * sizeof(unsigned int), stream);
    decode_kernel<<<dim3(NBLK), dim3(256), 0, stream>>>(y, ws);
    nms_kernel<<<dim3(1), dim3(256), 0, stream>>>(y, ws, (float*)d_out);
}